// Round 1
// baseline (111.335 us; speedup 1.0000x reference)
//
#include <hip/hip_runtime.h>

// BurstNeuron forward @ t==0, spike_mode=True, burst=True.
//
// Derivation (see round-0 analysis): the reference's global reduction
// n_global = max(min(k1, T+1)) never binds because for every element
// n_global >= min(k1, T+1) >= min(k1, T), hence
//   spike = min(k1, n_global, T) * th == min(k1, T) * th.
// Pure elementwise: mem0 = th/2 + x; k1 = mem0>th ? ceil((mem0-th)/th) : 0;
// out = min(k1, T) * th.  Memory-bound: 256 MiB in + 256 MiB out.

__global__ __launch_bounds__(256) void burst_neuron_kernel(
    const float4* __restrict__ x,
    const float4* __restrict__ th4,
    const int* __restrict__ Tp,
    float4* __restrict__ out,
    int nvec,          // total float4 count
    int cmask)         // (C/4 - 1), C/4 is a power of two
{
    const float Tf = (float)(*Tp);
    const int stride = gridDim.x * blockDim.x;

    for (int i = blockIdx.x * blockDim.x + threadIdx.x; i < nvec; i += stride) {
        const float4 xv = x[i];
        const float4 tv = th4[i & cmask];   // per-channel threshold, L1/L2 resident
        float4 o;

        #define BN_COMP(c)                                          \
        {                                                           \
            const float t   = tv.c;                                 \
            const float mem = t * 0.5f + xv.c;                      \
            float k = (mem > t) ? ceilf((mem - t) / t) : 0.0f;      \
            o.c = fminf(k, Tf) * t;                                 \
        }
        BN_COMP(x) BN_COMP(y) BN_COMP(z) BN_COMP(w)
        #undef BN_COMP

        out[i] = o;
    }
}

extern "C" void kernel_launch(void* const* d_in, const int* in_sizes, int n_in,
                              void* d_out, int out_size, void* d_ws, size_t ws_size,
                              hipStream_t stream) {
    const float4* x   = (const float4*)d_in[0];
    const float4* th4 = (const float4*)d_in[1];
    const int*    Tp  = (const int*)d_in[2];
    float4*       out = (float4*)d_out;

    const int nvec  = in_sizes[0] / 4;        // 16,777,216
    const int cvec  = in_sizes[1] / 4;        // 1024 (power of two)
    const int cmask = cvec - 1;

    const int block = 256;
    int grid = (nvec + block - 1) / block;
    if (grid > 2048) grid = 2048;             // 8 blocks/CU * 256 CUs, grid-stride the rest

    burst_neuron_kernel<<<grid, block, 0, stream>>>(x, th4, Tp, out, nvec, cmask);
}

// Round 3
// 103.160 us; speedup vs baseline: 1.0792x; 1.0792x over previous
//
#include <hip/hip_runtime.h>

// BurstNeuron forward @ t==0, spike_mode=True, burst=True.
//
// Derivation (round 0): the reference's global reduction n_global never binds:
//   spike = min(k1, n_global, T)*th == min(k1, T)*th.
// Pure elementwise: mem0 = th/2 + x; k1 = mem0>th ? ceil((mem0-th)/th) : 0;
// out = min(k1, T)*th.  Memory-bound: 256 MiB in + 256 MiB out, single touch
// each -> non-temporal streams; 16 KB threshold stays cached.
// Exact IEEE division kept (no fast-math) so ceil() matches the np reference
// bit-exactly (absmax was 0.0 in round 1).
//
// Round-2 fix: __builtin_nontemporal_load/store require a clang vector type,
// not HIP's struct float4 -> use ext_vector_type(4) float.

typedef float vfloat4 __attribute__((ext_vector_type(4)));

__global__ __launch_bounds__(256) void burst_neuron_kernel(
    const vfloat4* __restrict__ x,
    const vfloat4* __restrict__ th4,
    const int* __restrict__ Tp,
    vfloat4* __restrict__ out,
    int nvec,          // total float4 count
    int cmask)         // (C/4 - 1), C/4 is a power of two
{
    const float Tf = (float)(*Tp);
    const int stride = gridDim.x * blockDim.x;

    #define BN_ALL(o, tv, xv)                                       \
    {                                                               \
        for (int c = 0; c < 4; ++c) {                               \
            const float t   = tv[c];                                \
            const float mem = t * 0.5f + xv[c];                     \
            float k = (mem > t) ? ceilf((mem - t) / t) : 0.0f;      \
            o[c] = fminf(k, Tf) * t;                                \
        }                                                           \
    }

    int i = blockIdx.x * blockDim.x + threadIdx.x;

    // 2x-unrolled main loop: two independent load/compute/store chains per
    // iteration for memory-level parallelism.
    for (; i + stride < nvec; i += 2 * stride) {
        const int j = i + stride;
        const vfloat4 xa = __builtin_nontemporal_load(&x[i]);
        const vfloat4 xb = __builtin_nontemporal_load(&x[j]);
        const vfloat4 ta = th4[i & cmask];
        const vfloat4 tb = th4[j & cmask];
        vfloat4 oa, ob;
        BN_ALL(oa, ta, xa)
        BN_ALL(ob, tb, xb)
        __builtin_nontemporal_store(oa, &out[i]);
        __builtin_nontemporal_store(ob, &out[j]);
    }
    if (i < nvec) {
        const vfloat4 xa = __builtin_nontemporal_load(&x[i]);
        const vfloat4 ta = th4[i & cmask];
        vfloat4 oa;
        BN_ALL(oa, ta, xa)
        __builtin_nontemporal_store(oa, &out[i]);
    }

    #undef BN_ALL
}

extern "C" void kernel_launch(void* const* d_in, const int* in_sizes, int n_in,
                              void* d_out, int out_size, void* d_ws, size_t ws_size,
                              hipStream_t stream) {
    const vfloat4* x   = (const vfloat4*)d_in[0];
    const vfloat4* th4 = (const vfloat4*)d_in[1];
    const int*     Tp  = (const int*)d_in[2];
    vfloat4*       out = (vfloat4*)d_out;

    const int nvec  = in_sizes[0] / 4;        // 16,777,216
    const int cvec  = in_sizes[1] / 4;        // 1024 (power of two)
    const int cmask = cvec - 1;

    const int block = 256;
    int grid = (nvec + block - 1) / block;
    if (grid > 2048) grid = 2048;             // 8 blocks/CU, grid-stride the rest

    burst_neuron_kernel<<<grid, block, 0, stream>>>(x, th4, Tp, out, nvec, cmask);
}